// Round 21
// baseline (168.378 us; speedup 1.0000x reference)
//
#include <hip/hip_runtime.h>

namespace {
constexpr int H = 544, W = 960, D = 64, NB = 2;
constexpr long SL   = (long)H * W;        // per-batch image elems
constexpr long W64  = (long)W * 64;       // row stride in out1 elems
constexpr long CHUNK_B = (long)H * W64 * 4;   // per-batch intermediate: 134 MB
}

// ===========================================================================
// Bitwise replica of XLA ReduceWindowRewriter base-16 cumsum (verified
// r12-r20). This round: batch-split pipeline -- per-batch out1 chunk (134 MB,
// Infinity-Cache-resident) reused across batches. Kernels verbatim r20
// modulo the batch argument / halved grids.
// ===========================================================================

__device__ __forceinline__ void fold16(float& o1p, float& o2, int& c, int& a,
                                       float tot) {
  o1p = (c == 0) ? tot : (o1p + tot);
  if (++c == 16) { o2 = (a == 0) ? o1p : (o2 + o1p); ++a; c = 0; }
}
__device__ __forceinline__ float baseof(float o1p, float o2, int c, int a) {
  return (a == 0) ? ((c == 0) ? 0.f : o1p) : ((c == 0) ? o2 : (o2 + o1p));
}

#define TILE_FULL()                                                          \
  {                                                                          \
    const float base =                                                       \
        (a == 0) ? ((c == 0) ? 0.f : o1p) : ((c == 0) ? o2 : (o2 + o1p));    \
    float ip = wc[0];                                                        \
    oc_[0] = base + ip;                                                      \
    _Pragma("unroll") for (int j = 1; j < 16; ++j) {                         \
      ip += wc[j];                                                           \
      oc_[j] = base + ip;                                                    \
    }                                                                        \
    o1p = (c == 0) ? ip : (o1p + ip);                                        \
    if (++c == 16) { o2 = (a == 0) ? o1p : (o2 + o1p); ++a; c = 0; }         \
  }

#define TILE_PART14()                                                        \
  {                                                                          \
    const float base =                                                       \
        (a == 0) ? ((c == 0) ? 0.f : o1p) : ((c == 0) ? o2 : (o2 + o1p));    \
    float ip = wc[0];                                                        \
    oc_[0] = base + ip;                                                      \
    _Pragma("unroll") for (int j = 1; j < 14; ++j) {                         \
      ip += wc[j];                                                           \
      oc_[j] = base + ip;                                                    \
    }                                                                        \
  }

#define ROT()                                                                \
  _Pragma("unroll") for (int j = 0; j < 16; ++j) {                           \
    op_[j] = oc_[j];                                                         \
    wc[j] = wn[j];                                                           \
  }

// ---------------------------------------------------------------------------
// Phase 1: vertical box for ONE batch -> out1[y][x][d]. Thread = (x, lane=d).
// ---------------------------------------------------------------------------
__global__ __launch_bounds__(256) void vbox_t(
    const float* __restrict__ Lp, const float* __restrict__ Rp,
    float* __restrict__ out1, int b) {
  const int t  = blockIdx.x * 256 + threadIdx.x;   // W*64 threads
  const int dc = t & 63;
  const int x  = t >> 6;
  const int xs = max(x - dc, 0);
  const float* Lc = Lp + (long)b * SL + x;
  const float* Rc = Rp + (long)b * SL + xs;
  float* Ob = out1 + (long)x * 64 + dc;

  float o1p = 0.f, o2 = 0.f;
  int c = 0, a = 0;
  float wc[16], wn[16], oc_[16], op_[16];

#pragma unroll
  for (int j = 0; j < 16; ++j) {
    const long yy = j - 7;
    wc[j] = (j >= 7) ? fabsf(Lc[yy * W] - Rc[yy * W]) : 0.f;
  }
#pragma unroll
  for (int j = 0; j < 16; ++j) {
    const long yy = 9 + j;
    wn[j] = fabsf(Lc[yy * W] - Rc[yy * W]);
  }
  TILE_FULL();
  Ob[0]   = oc_[14];
  Ob[W64] = oc_[15] - oc_[0];
  ROT();

#pragma unroll 1
  for (int tt = 1; tt <= 32; ++tt) {
#pragma unroll
    for (int j = 0; j < 16; ++j) {
      const long yy = 16 * (tt + 1) + j - 7;
      wn[j] = fabsf(Lc[yy * W] - Rc[yy * W]);
    }
    TILE_FULL();
#pragma unroll
    for (int j = 0; j < 16; ++j) {
      const float lo = (j < 15) ? op_[j + 1] : oc_[0];
      const long e = 16 * tt + j - 14;
      Ob[e * W64] = oc_[j] - lo;
    }
    ROT();
  }

#pragma unroll
  for (int j = 0; j < 16; ++j) {
    const long yy = 537 + j;
    wn[j] = (j <= 6) ? fabsf(Lc[yy * W] - Rc[yy * W]) : 0.f;
  }
  TILE_FULL();
#pragma unroll
  for (int j = 0; j < 16; ++j) {
    const float lo = (j < 15) ? op_[j + 1] : oc_[0];
    const long e = 16 * 33 + j - 14;
    Ob[e * W64] = oc_[j] - lo;
  }
  ROT();

  TILE_PART14();
#pragma unroll
  for (int j = 0; j < 14; ++j) {
    const long e = 530 + j;
    Ob[e * W64] = oc_[j] - op_[j + 1];
  }
}

// ---------------------------------------------------------------------------
// Phase 2: horizontal box + argmin for ONE batch. Block = y, 8 waves; lane=d.
// Verbatim r20 (verified): phase-A totals -> replay fold -> LDS-transpose
// argmin (first-occurrence preserved bitwise).
// ---------------------------------------------------------------------------
__global__ __launch_bounds__(512) void hbox_p8(
    const float* __restrict__ out1, int* __restrict__ out, int b) {
  __shared__ float lds[8 * 16 * 68];               // 34.8 KB union
  float (*T)[64] = reinterpret_cast<float (*)[64]>(lds);
  const int lane = threadIdx.x & 63;
  const int w    = threadIdx.x >> 6;
  float* clw = lds + w * (16 * 68);
  const int y = blockIdx.x;
  const float* __restrict__ rowp = out1 + (long)y * W64 + lane;
  int* __restrict__ orow = out + (long)b * SL + (long)y * W;

  auto ldtile = [&](int t, float (&vv)[16]) {
#pragma unroll
    for (int j = 0; j < 16; ++j) {
      const int xsrc = 16 * t + j - 7;
      vv[j] = (xsrc >= 0 && xsrc < W) ? rowp[(long)xsrc * 64] : 0.f;
    }
  };

  const int t0   = (w < 5) ? 8 * w : 40 + 7 * (w - 5);   // 0,8,16,24,32,40,47,54
  const int tend = t0 + ((w < 5) ? 8 : 7);

  // ---- phase A: owned-tile totals (identical 16-add order) ----
  for (int t = t0; t < tend; ++t) {
    float vv[16];
    ldtile(t, vv);
    float s = vv[0];
#pragma unroll
    for (int j = 1; j < 16; ++j) s += vv[j];
    T[t][lane] = s;
  }
  __syncthreads();

  // ---- replay fold to entry state ----
  float o1p = 0.f, o2 = 0.f;
  int c = 0, a = 0;
  for (int tp = 0; tp + 1 < t0; ++tp) fold16(o1p, o2, c, a, T[tp][lane]);

  float poc[16];
  if (w > 0) {                                     // recompute tile t0-1 scan
    const float base_prev = baseof(o1p, o2, c, a);
    fold16(o1p, o2, c, a, T[t0 - 1][lane]);
    float vv[16];
    ldtile(t0 - 1, vv);
    float ipp = vv[0];
    poc[0] = base_prev + ipp;
#pragma unroll
    for (int j = 1; j < 16; ++j) { ipp += vv[j]; poc[j] = base_prev + ipp; }
  }
  float base = baseof(o1p, o2, c, a);
  __syncthreads();                                 // T dead -> cl region live

  const int xsl = lane & 15, g = lane >> 4;
  float* rdp = clw + xsl * 68 + g * 16;

  for (int t = t0; t < tend; ++t) {
    float vv[16];
    ldtile(t, vv);
    float oc_[16];
    float ip = vv[0];
    oc_[0] = base + ip;
#pragma unroll
    for (int j = 1; j < 16; ++j) { ip += vv[j]; oc_[j] = base + ip; }

    if (t == 0) {
      clw[0 * 68 + lane] = oc_[14];                // e = 0 (lo = 0)
      clw[1 * 68 + lane] = oc_[15] - oc_[0];       // e = 1
#pragma unroll
      for (int j = 2; j < 16; ++j) clw[j * 68 + lane] = 3.0e38f;
    } else if (t == 60) {
#pragma unroll
      for (int j = 0; j < 14; ++j) clw[j * 68 + lane] = oc_[j] - poc[j + 1];
      clw[14 * 68 + lane] = 3.0e38f;
      clw[15 * 68 + lane] = 3.0e38f;
    } else {
#pragma unroll
      for (int j = 0; j < 16; ++j)
        clw[j * 68 + lane] = oc_[j] - ((j < 15) ? poc[j + 1] : oc_[0]);
    }

    const float4 f0 = *reinterpret_cast<const float4*>(rdp);
    const float4 f1 = *reinterpret_cast<const float4*>(rdp + 4);
    const float4 f2 = *reinterpret_cast<const float4*>(rdp + 8);
    const float4 f3 = *reinterpret_cast<const float4*>(rdp + 12);
    const float vals[16] = {f0.x, f0.y, f0.z, f0.w, f1.x, f1.y, f1.z, f1.w,
                            f2.x, f2.y, f2.z, f2.w, f3.x, f3.y, f3.z, f3.w};
    float m = vals[0];
    int  md = 16 * g;
#pragma unroll
    for (int k = 1; k < 16; ++k)
      if (vals[k] < m) { m = vals[k]; md = 16 * g + k; }

#pragma unroll
    for (int off = 16; off <= 32; off <<= 1) {
      const float om  = __shfl_xor(m, off);
      const int   omd = __shfl_xor(md, off);
      if (om < m || (om == m && omd < md)) { m = om; md = omd; }
    }

    if (t == 0)       { if (lane < 2)  orow[lane] = md; }
    else if (t == 60) { if (lane < 14) orow[946 + lane] = md; }
    else              { if (lane < 16) orow[16 * t - 14 + lane] = md; }

    if (t + 1 < tend) {
      fold16(o1p, o2, c, a, ip);
      base = baseof(o1p, o2, c, a);
#pragma unroll
      for (int j = 0; j < 16; ++j) poc[j] = oc_[j];
    }
  }
}

extern "C" void kernel_launch(void* const* d_in, const int* in_sizes, int n_in,
                              void* d_out, int out_size, void* d_ws, size_t ws_size,
                              hipStream_t stream) {
  const float* L = (const float*)d_in[0];
  const float* R = (const float*)d_in[1];
  int* out = (int*)d_out;
  if (ws_size < (size_t)CHUNK_B) return;           // 134 MB per-batch chunk
  float* out1 = (float*)d_ws;                      // reused for both batches

  for (int b = 0; b < NB; ++b) {
    vbox_t<<<(W * 64) / 256, 256, 0, stream>>>(L, R, out1, b);
    hbox_p8<<<dim3(H), 512, 0, stream>>>(out1, out, b);
  }
}